// Round 1
// 909.457 us; speedup vs baseline: 1.0288x; 1.0288x over previous
//
#include <hip/hip_runtime.h>
#include <math.h>

#define BATCH 256
#define D 512
#define WPROW ((size_t)(D * D)) // 262144 floats per Wp row
#define NTILE 64                // Wp rows (output cols) per WG
#define BK 64                   // fp32 per row per K-chunk (256 B)
#define NCHUNK 64               // 8 i-values * 8 j-groups
#define NBUF 4                  // LDS ring buffers
#define PFD 3                   // prefetch depth (chunks in flight)

typedef __bf16  bf16x8  __attribute__((ext_vector_type(8)));
typedef float   floatx4 __attribute__((ext_vector_type(4)));

// ---------------- Kernel 1: mapping Linear + L2 normalize ----------------
__global__ __launch_bounds__(256)
void map_norm_kernel(const float* __restrict__ img_emb,
                     const float* __restrict__ txt_emb,
                     const float* __restrict__ Wi, const float* __restrict__ bi,
                     const float* __restrict__ Wt, const float* __restrict__ bt,
                     float* __restrict__ imgT,
                     float* __restrict__ txtN)
{
    const int b = blockIdx.x;
    const int is_txt = blockIdx.y;
    const int t = threadIdx.x;
    const float* emb = is_txt ? txt_emb : img_emb;
    const float* W   = is_txt ? Wt : Wi;
    const float* bv  = is_txt ? bt : bi;

    __shared__ float row[D];
    row[t]       = emb[(size_t)b * D + t];
    row[t + 256] = emb[(size_t)b * D + t + 256];
    __syncthreads();

    const int k0 = t, k1 = t + 256;
    float acc0 = bv[k0], acc1 = bv[k1];
    const float4* w0 = (const float4*)(W + (size_t)k0 * D);
    const float4* w1 = (const float4*)(W + (size_t)k1 * D);
    const float4* r4 = (const float4*)row;
#pragma unroll 8
    for (int p = 0; p < D / 4; ++p) {
        float4 rv = r4[p];
        float4 a  = w0[p];
        float4 c  = w1[p];
        acc0 += a.x * rv.x + a.y * rv.y + a.z * rv.z + a.w * rv.w;
        acc1 += c.x * rv.x + c.y * rv.y + c.z * rv.z + c.w * rv.w;
    }

    float ss = acc0 * acc0 + acc1 * acc1;
#pragma unroll
    for (int o = 32; o > 0; o >>= 1) ss += __shfl_down(ss, o);
    __shared__ float red[4];
    if ((t & 63) == 0) red[t >> 6] = ss;
    __syncthreads();
    float total = red[0] + red[1] + red[2] + red[3];
    float inv = 1.0f / fmaxf(sqrtf(total), 1e-12f);
    float v0 = acc0 * inv, v1 = acc1 * inv;

    if (is_txt) {
        txtN[(size_t)b * D + k0] = v0;
        txtN[(size_t)b * D + k1] = v1;
    } else {
        imgT[(size_t)k0 * BATCH + b] = v0;
        imgT[(size_t)k1 * BATCH + b] = v1;
    }
}

// ---------------- Kernel 2: streaming bilinear GEMM, ring-buffered -------
// C[b,k] = sum_c P[b,c]*Wp[k,c], P[b,i*512+j] = img[b,i]*txt[b,j].
// 512 WGs (2/CU): nt = wg&7 picks 64 Wp rows, ks = wg>>3 picks 4096 K-cols
// (8 i-values x all 512 j). Chunk order is i-FAST (i = c&7, jb = (c>>3)*64)
// so each wave's txt A-fragments are constant for 8 consecutive chunks and
// live in 64 VGPRs; all 32 img scales are register-cached for the whole WG.
// Steady-state loop therefore issues NO vmem except the Wp DMA, letting the
// counted s_waitcnt vmcnt(8) keep 3 chunks (48 KB/WG) in flight across raw
// s_barriers — no vmcnt(0) drain until the tail (T3/T4).
__global__ __launch_bounds__(256, 2)
void bilinear_kernel(const float* __restrict__ txtN,  // [BATCH][D]
                     const float* __restrict__ imgT,  // [D][BATCH]
                     const float* __restrict__ Wp,    // [D][D*D]
                     float* __restrict__ feats)       // [BATCH][D], pre-zeroed
{
    __shared__ float lds[NBUF][NTILE * BK];   // 4 x 16 KB

    const int wg   = blockIdx.x;
    const int nt   = wg & 7;
    const int ks   = wg >> 3;
    const int tid  = threadIdx.x;
    const int lane = tid & 63;
    const int wave = tid >> 6;
    const int lane15 = lane & 15;
    const int quad   = lane >> 4;

    const int n0    = nt * NTILE;
    const int i0    = ks * 8;
    const int brow0 = wave * 64 + lane15;

    // DMA lane mapping: one 1KB instr = 4 rows x 16 16B-slots, linear LDS.
    const int dma_rowoff = lane >> 4;   // 0..3
    const int dma_slot   = lane & 15;

    floatx4 acc[4][4];
#pragma unroll
    for (int m = 0; m < 4; ++m)
#pragma unroll
        for (int n = 0; n < 4; ++n) acc[m][n] = (floatx4){0.f, 0.f, 0.f, 0.f};

    // img scales for the WG's entire i-range: simg[il][m], 32 VGPRs.
    float simg[8][4];
#pragma unroll
    for (int il = 0; il < 8; ++il)
#pragma unroll
        for (int m = 0; m < 4; ++m)
            simg[il][m] = imgT[(size_t)(i0 + il) * BATCH + brow0 + m * 16];

    // txt fragments for the current j-group (f32, pre-scale): 64 VGPRs.
    float4 ta[2][4][2];
    auto refresh = [&](int jg) {
#pragma unroll
        for (int t = 0; t < 2; ++t)
#pragma unroll
            for (int m = 0; m < 4; ++m) {
                const float4* p = (const float4*)(txtN +
                    (size_t)(brow0 + m * 16) * D + jg * 64 + t * 32 + quad * 8);
                ta[t][m][0] = p[0];
                ta[t][m][1] = p[1];
            }
    };

    // Stage one 16 KB Wp chunk via global_load_lds (4 instr/wave), with
    // fetch-side XOR swizzle by (row&7) on the 16B slot index.
    auto stage = [&](int c) {
        const int    bufs = c & (NBUF - 1);
        const size_t kb   = (size_t)(i0 + (c & 7)) * D + (size_t)(c >> 3) * BK;
#pragma unroll
        for (int u = 0; u < 4; ++u) {
            const int rbase = wave * 16 + u * 4;
            const int row   = rbase + dma_rowoff;
            const int slot  = dma_slot ^ (row & 7);
            const float* gp = Wp + (size_t)(n0 + row) * WPROW + kb + slot * 4;
            float* lp = &lds[bufs][rbase * BK];
            __builtin_amdgcn_global_load_lds(
                (__attribute__((address_space(1))) void*)(uintptr_t)gp,
                (__attribute__((address_space(3))) void*)(uintptr_t)lp,
                16, 0, 0);
        }
    };

    refresh(0);
    stage(0); stage(1); stage(2);   // 12 DMA in flight

#pragma unroll 1
    for (int g = 0; g < 8; ++g) {
#pragma unroll
        for (int il = 0; il < 8; ++il) {
            const int c = g * 8 + il;

            // Counted wait: own chunk-c DMAs done, c+1/c+2 stay in flight.
            // (Per-wave FIFO vmcnt; steady-state outstanding = 12.)
            if (il <= 5) {
                asm volatile("s_waitcnt vmcnt(8)" ::: "memory");
            } else if (il == 6) {
                if (g == 7) asm volatile("s_waitcnt vmcnt(4)" ::: "memory");
                else        asm volatile("s_waitcnt vmcnt(8)" ::: "memory");
            } else {
                if (g == 7) asm volatile("s_waitcnt vmcnt(0)" ::: "memory");
                else        asm volatile("s_waitcnt vmcnt(8)" ::: "memory");
            }
            __builtin_amdgcn_s_barrier();       // all waves' chunk-c DMA done
            asm volatile("" ::: "memory");      // keep ds_read/DMA below bar

            // New j-group: reload txt frags (before stage -> compiler waits
            // them with vmcnt(4), only a shallow pipeline dip, 8x per WG).
            if (il == 0 && g > 0) refresh(g);
            if (c + PFD < NCHUNK) stage(c + PFD);   // overwrites buf of c-1

            const float* Bt = &lds[c & (NBUF - 1)][0];
#pragma unroll
            for (int t = 0; t < 2; ++t) {
                const int bc = t * 8 + quad * 2;    // 16B-slot index
                bf16x8 bfr[4];
#pragma unroll
                for (int n = 0; n < 4; ++n) {
                    const int r  = n * 16 + lane15;
                    const int sw = r & 7;
                    const float4 x = *(const float4*)(Bt + r * BK + ((bc    ) ^ sw) * 4);
                    const float4 y = *(const float4*)(Bt + r * BK + ((bc + 1) ^ sw) * 4);
                    bf16x8 v;
                    v[0] = (__bf16)x.x; v[1] = (__bf16)x.y;
                    v[2] = (__bf16)x.z; v[3] = (__bf16)x.w;
                    v[4] = (__bf16)y.x; v[5] = (__bf16)y.y;
                    v[6] = (__bf16)y.z; v[7] = (__bf16)y.w;
                    bfr[n] = v;
                }
#pragma unroll
                for (int m = 0; m < 4; ++m) {
                    const float  s  = simg[il][m];
                    const float4 u0 = ta[t][m][0], u1 = ta[t][m][1];
                    bf16x8 a;
                    a[0] = (__bf16)(s * u0.x); a[1] = (__bf16)(s * u0.y);
                    a[2] = (__bf16)(s * u0.z); a[3] = (__bf16)(s * u0.w);
                    a[4] = (__bf16)(s * u1.x); a[5] = (__bf16)(s * u1.y);
                    a[6] = (__bf16)(s * u1.z); a[7] = (__bf16)(s * u1.w);
#pragma unroll
                    for (int n = 0; n < 4; ++n)
                        acc[m][n] = __builtin_amdgcn_mfma_f32_16x16x32_bf16(
                            a, bfr[n], acc[m][n], 0, 0, 0);
                }
            }
        }
    }

    // Split-K reduction. C/D layout: col = lane&15, row = quad*4 + reg.
#pragma unroll
    for (int m = 0; m < 4; ++m)
#pragma unroll
        for (int n = 0; n < 4; ++n)
#pragma unroll
            for (int r = 0; r < 4; ++r) {
                int brow = wave * 64 + m * 16 + quad * 4 + r;
                int kcol = n0 + n * 16 + lane15;
                atomicAdd(&feats[(size_t)brow * D + kcol], acc[m][n][r]);
            }
}

// ---------------- Kernel 3: bias + ReLU + classifier + sigmoid ------------
__global__ __launch_bounds__(256)
void epilogue_kernel(const float* __restrict__ feats,
                     const float* __restrict__ bp,
                     const float* __restrict__ Wc,
                     const float* __restrict__ bc,
                     float* __restrict__ out)
{
    const int b = blockIdx.x;
    const int t = threadIdx.x;
    float v0 = fmaxf(feats[(size_t)b * D + t] + bp[t], 0.f) * Wc[t];
    float v1 = fmaxf(feats[(size_t)b * D + t + 256] + bp[t + 256], 0.f) * Wc[t + 256];
    float s = v0 + v1;
#pragma unroll
    for (int o = 32; o > 0; o >>= 1) s += __shfl_down(s, o);
    __shared__ float red[4];
    if ((t & 63) == 0) red[t >> 6] = s;
    __syncthreads();
    if (t == 0) {
        float tot = red[0] + red[1] + red[2] + red[3] + bc[0];
        out[b] = 1.0f / (1.0f + expf(-tot));
    }
}

extern "C" void kernel_launch(void* const* d_in, const int* in_sizes, int n_in,
                              void* d_out, int out_size, void* d_ws, size_t ws_size,
                              hipStream_t stream) {
    const float* image_embeds = (const float*)d_in[0];
    const float* text_embeds  = (const float*)d_in[1];
    const float* Wi = (const float*)d_in[2];
    const float* bi = (const float*)d_in[3];
    const float* Wt = (const float*)d_in[4];
    const float* bt = (const float*)d_in[5];
    const float* Wp = (const float*)d_in[6];
    const float* bp = (const float*)d_in[7];
    const float* Wc = (const float*)d_in[8];
    const float* bc = (const float*)d_in[9];
    float* out = (float*)d_out;

    float* txtN  = (float*)d_ws;            // 256*512 f32
    float* imgT  = txtN + BATCH * D;        // 512*256 f32
    float* feats = imgT + D * BATCH;        // 256*512 f32

    hipMemsetAsync(feats, 0, (size_t)BATCH * D * sizeof(float), stream);
    map_norm_kernel<<<dim3(BATCH, 2), 256, 0, stream>>>(
        image_embeds, text_embeds, Wi, bi, Wt, bt, imgT, txtN);
    bilinear_kernel<<<dim3(512), 256, 0, stream>>>(txtN, imgT, Wp, feats);
    epilogue_kernel<<<dim3(BATCH), 256, 0, stream>>>(feats, bp, Wc, bc, out);
}

// Round 2
// 792.742 us; speedup vs baseline: 1.1802x; 1.1472x over previous
//
#include <hip/hip_runtime.h>
#include <math.h>

#define BATCH 256
#define D 512
#define WPROW ((size_t)(D * D)) // 262144 floats per Wp row
#define NTILE 16                // Wp rows (output cols) per WG
#define NI    16                // i-values per WG
#define NBUF  3                 // LDS ring buffers
#define NCHUNK 32               // 2 j-halves x 16 i

typedef __bf16  bf16x8  __attribute__((ext_vector_type(8)));
typedef float   floatx4 __attribute__((ext_vector_type(4)));

// ---------------- Kernel 1: mapping Linear + L2 normalize ----------------
__global__ __launch_bounds__(256)
void map_norm_kernel(const float* __restrict__ img_emb,
                     const float* __restrict__ txt_emb,
                     const float* __restrict__ Wi, const float* __restrict__ bi,
                     const float* __restrict__ Wt, const float* __restrict__ bt,
                     float* __restrict__ imgT,
                     float* __restrict__ txtN)
{
    const int b = blockIdx.x;
    const int is_txt = blockIdx.y;
    const int t = threadIdx.x;
    const float* emb = is_txt ? txt_emb : img_emb;
    const float* W   = is_txt ? Wt : Wi;
    const float* bv  = is_txt ? bt : bi;

    __shared__ float row[D];
    row[t]       = emb[(size_t)b * D + t];
    row[t + 256] = emb[(size_t)b * D + t + 256];
    __syncthreads();

    const int k0 = t, k1 = t + 256;
    float acc0 = bv[k0], acc1 = bv[k1];
    const float4* w0 = (const float4*)(W + (size_t)k0 * D);
    const float4* w1 = (const float4*)(W + (size_t)k1 * D);
    const float4* r4 = (const float4*)row;
#pragma unroll 8
    for (int p = 0; p < D / 4; ++p) {
        float4 rv = r4[p];
        float4 a  = w0[p];
        float4 c  = w1[p];
        acc0 += a.x * rv.x + a.y * rv.y + a.z * rv.z + a.w * rv.w;
        acc1 += c.x * rv.x + c.y * rv.y + c.z * rv.z + c.w * rv.w;
    }

    float ss = acc0 * acc0 + acc1 * acc1;
#pragma unroll
    for (int o = 32; o > 0; o >>= 1) ss += __shfl_down(ss, o);
    __shared__ float red[4];
    if ((t & 63) == 0) red[t >> 6] = ss;
    __syncthreads();
    float total = red[0] + red[1] + red[2] + red[3];
    float inv = 1.0f / fmaxf(sqrtf(total), 1e-12f);
    float v0 = acc0 * inv, v1 = acc1 * inv;

    if (is_txt) {
        txtN[(size_t)b * D + k0] = v0;
        txtN[(size_t)b * D + k1] = v1;
    } else {
        imgT[(size_t)k0 * BATCH + b] = v0;
        imgT[(size_t)k1 * BATCH + b] = v1;
    }
}

// ---------------- Kernel 2: streaming bilinear GEMM, sequential DMA -------
// C[b,k] = sum_{i,j} img[b,i]*txt[b,j]*Wp[k, i*512+j].
// 1024 WGs: nt = wg&31 picks 16 Wp rows, ks = wg>>5 picks 16 i-values.
// Chunk = (j-half, i): 16 rows x 1 KB CONTIGUOUS per row (one DMA instr per
// row: single page, sequential burst) -- fixes the 256B@1MiB-stride gather
// that capped delivery at 1.6 TB/s. img scale is applied on the ACCUMULATOR
// (acc += img[b,i]*cacc) so the A-fragment = bf16(txt) is constant per
// j-half (128 VGPR, one mid-kernel refresh) and the steady-state loop has
// no VMEM except the Wp DMA -> counted vmcnt(4) stays exact.
__global__ __launch_bounds__(256, 2)
void bilinear_kernel(const float* __restrict__ txtN,  // [BATCH][D]
                     const float* __restrict__ imgT,  // [D][BATCH]
                     const float* __restrict__ Wp,    // [D][D*D]
                     float* __restrict__ feats)       // [BATCH][D], pre-zeroed
{
    __shared__ float wbuf[NBUF][NTILE * 256];  // 3 x 16 KB ring
    __shared__ float simgL[NI * BATCH];        // 16 KB img scales (f32)

    const int wg   = blockIdx.x;
    const int nt   = wg & 31;
    const int ks   = wg >> 5;
    const int tid  = threadIdx.x;
    const int lane = tid & 63;
    const int wave = tid >> 6;
    const int lane15 = lane & 15;
    const int quad   = lane >> 4;

    const int n0    = nt * NTILE;
    const int i0    = ks * NI;
    const int brow0 = wave * 64 + lane15;

    floatx4 acc[4];
#pragma unroll
    for (int m = 0; m < 4; ++m) acc[m] = (floatx4){0.f, 0.f, 0.f, 0.f};

    // A-fragments: bf16(txt) for the current j-half. afr[m][k8], 128 VGPR.
    bf16x8 afr[4][8];
    auto loadA = [&](int jh) {
#pragma unroll
        for (int m = 0; m < 4; ++m)
#pragma unroll
            for (int k8 = 0; k8 < 8; ++k8) {
                const float4* p = (const float4*)(txtN +
                    (size_t)(brow0 + m * 16) * D + jh * 256 + k8 * 32 + quad * 8);
                float4 u0 = p[0], u1 = p[1];
                bf16x8 a;
                a[0] = (__bf16)u0.x; a[1] = (__bf16)u0.y;
                a[2] = (__bf16)u0.z; a[3] = (__bf16)u0.w;
                a[4] = (__bf16)u1.x; a[5] = (__bf16)u1.y;
                a[6] = (__bf16)u1.z; a[7] = (__bf16)u1.w;
                afr[m][k8] = a;
            }
    };

    // Stage chunk c: 16 rows x 1 KB, one global_load_lds per row (64 lanes
    // x 16 B sequential). Fetch-side XOR swizzle of the 16B slot by (row&7)
    // so the strided ds_read_b128 frag reads are bank-conflict-free.
    auto stage = [&](int c, int buf) {
        const int    i       = c & 15;
        const int    jh      = c >> 4;
        const size_t colbase = (size_t)(i0 + i) * D + jh * 256;
#pragma unroll
        for (int u = 0; u < 4; ++u) {
            const int r     = wave * 4 + u;
            const int gslot = lane ^ (r & 7);
            const float* gp = Wp + (size_t)(n0 + r) * WPROW + colbase + gslot * 4;
            float* lp = &wbuf[buf][r * 256];
            __builtin_amdgcn_global_load_lds(
                (__attribute__((address_space(1))) void*)(uintptr_t)gp,
                (__attribute__((address_space(3))) void*)(uintptr_t)lp,
                16, 0, 0);
        }
    };

    loadA(0);
    // Stage img scales for the WG's i-range into LDS (f32, full precision).
#pragma unroll
    for (int i = 0; i < NI; ++i)
        simgL[i * BATCH + tid] = imgT[(size_t)(i0 + i) * BATCH + tid];
    __syncthreads();            // drains all prologue vmem + LDS writes

    stage(0, 0);
    stage(1, 1);                // 8 DMA outstanding per wave

    int bcur = 0;
#pragma unroll 1
    for (int c = 0; c < NCHUNK; ++c) {
        // Counted wait: own chunk-c DMAs (oldest 4) done; chunk c+1 stays
        // in flight across the barrier. Drain to 0 only at the tail.
        if (c < NCHUNK - 1) asm volatile("s_waitcnt vmcnt(4)" ::: "memory");
        else                asm volatile("s_waitcnt vmcnt(0)" ::: "memory");
        __builtin_amdgcn_s_barrier();       // all waves' chunk-c DMA done
        asm volatile("" ::: "memory");      // keep LDS reads below barrier

        // j-half switch: refresh A-frags (compiler-waited; one-time drain).
        if (c == 16) loadA(1);
        if (c + 2 < NCHUNK) {
            int b2 = bcur + 2; if (b2 >= NBUF) b2 -= NBUF;
            stage(c + 2, b2);               // overwrites buffer of chunk c-1
        }

        const float* Bt = &wbuf[bcur][0];
        floatx4 cacc[4];
#pragma unroll
        for (int m = 0; m < 4; ++m) cacc[m] = (floatx4){0.f, 0.f, 0.f, 0.f};

#pragma unroll
        for (int k8 = 0; k8 < 8; ++k8) {
            const int r  = lane15;
            const int sw = r & 7;
            const int s6 = k8 * 8 + quad * 2;
            const float4 x = *(const float4*)(Bt + r * 256 + ((s6    ) ^ sw) * 4);
            const float4 y = *(const float4*)(Bt + r * 256 + ((s6 + 1) ^ sw) * 4);
            bf16x8 b;
            b[0] = (__bf16)x.x; b[1] = (__bf16)x.y;
            b[2] = (__bf16)x.z; b[3] = (__bf16)x.w;
            b[4] = (__bf16)y.x; b[5] = (__bf16)y.y;
            b[6] = (__bf16)y.z; b[7] = (__bf16)y.w;
#pragma unroll
            for (int m = 0; m < 4; ++m)
                cacc[m] = __builtin_amdgcn_mfma_f32_16x16x32_bf16(
                    afr[m][k8], b, cacc[m], 0, 0, 0);
        }

        // Fold with per-(b,i) img scale from LDS (f32, broadcast reads).
        const int ci = c & 15;
#pragma unroll
        for (int m = 0; m < 4; ++m) {
            const float4 sc = *(const float4*)(
                &simgL[ci * BATCH + wave * 64 + m * 16 + quad * 4]);
            acc[m][0] += sc.x * cacc[m][0];
            acc[m][1] += sc.y * cacc[m][1];
            acc[m][2] += sc.z * cacc[m][2];
            acc[m][3] += sc.w * cacc[m][3];
        }

        ++bcur; if (bcur == NBUF) bcur = 0;
    }

    // Split-K reduction. C/D layout: col = lane&15, row = quad*4 + reg.
#pragma unroll
    for (int m = 0; m < 4; ++m)
#pragma unroll
        for (int r = 0; r < 4; ++r) {
            int brow = wave * 64 + m * 16 + quad * 4 + r;
            int kcol = n0 + lane15;
            atomicAdd(&feats[(size_t)brow * D + kcol], acc[m][r]);
        }
}

// ---------------- Kernel 3: bias + ReLU + classifier + sigmoid ------------
__global__ __launch_bounds__(256)
void epilogue_kernel(const float* __restrict__ feats,
                     const float* __restrict__ bp,
                     const float* __restrict__ Wc,
                     const float* __restrict__ bc,
                     float* __restrict__ out)
{
    const int b = blockIdx.x;
    const int t = threadIdx.x;
    float v0 = fmaxf(feats[(size_t)b * D + t] + bp[t], 0.f) * Wc[t];
    float v1 = fmaxf(feats[(size_t)b * D + t + 256] + bp[t + 256], 0.f) * Wc[t + 256];
    float s = v0 + v1;
#pragma unroll
    for (int o = 32; o > 0; o >>= 1) s += __shfl_down(s, o);
    __shared__ float red[4];
    if ((t & 63) == 0) red[t >> 6] = s;
    __syncthreads();
    if (t == 0) {
        float tot = red[0] + red[1] + red[2] + red[3] + bc[0];
        out[b] = 1.0f / (1.0f + expf(-tot));
    }
}

extern "C" void kernel_launch(void* const* d_in, const int* in_sizes, int n_in,
                              void* d_out, int out_size, void* d_ws, size_t ws_size,
                              hipStream_t stream) {
    const float* image_embeds = (const float*)d_in[0];
    const float* text_embeds  = (const float*)d_in[1];
    const float* Wi = (const float*)d_in[2];
    const float* bi = (const float*)d_in[3];
    const float* Wt = (const float*)d_in[4];
    const float* bt = (const float*)d_in[5];
    const float* Wp = (const float*)d_in[6];
    const float* bp = (const float*)d_in[7];
    const float* Wc = (const float*)d_in[8];
    const float* bc = (const float*)d_in[9];
    float* out = (float*)d_out;

    float* txtN  = (float*)d_ws;            // 256*512 f32
    float* imgT  = txtN + BATCH * D;        // 512*256 f32
    float* feats = imgT + D * BATCH;        // 256*512 f32

    hipMemsetAsync(feats, 0, (size_t)BATCH * D * sizeof(float), stream);
    map_norm_kernel<<<dim3(BATCH, 2), 256, 0, stream>>>(
        image_embeds, text_embeds, Wi, bi, Wt, bt, imgT, txtN);
    bilinear_kernel<<<dim3(1024), 256, 0, stream>>>(txtN, imgT, Wp, feats);
    epilogue_kernel<<<dim3(BATCH), 256, 0, stream>>>(feats, bp, Wc, bc, out);
}